// Round 12
// baseline (246.318 us; speedup 1.0000x reference)
//
#include <hip/hip_runtime.h>
#include <hip/hip_bf16.h>

// EncoderLayer: B=2, S=2048, D_MODEL=512, H=8, D_FF=2048
// Round 12: r11 DMA regressed (245us): DMA has no pipelining - vmcnt(0)
// drain exposes full global latency every iter (r10's reg-prefetch hid it).
// This round = r10 register-prefetch staging + (a) double-buffered LDS with
// ONE barrier/iter (write buf[k&1] races only with iter k-2 readers, who are
// fenced by iter k-1's barrier), (b) chunk-major unpadded LDS [c][rows][8]
// (2-way = free; smaller: dbuf 48KB @BM=128 -> 3 blk/CU, 32KB @BM=64 -> 5).
// Attention (r10, 44us), prep, LN unchanged.
// ws (MiB): q[0,4)->attn_out; k[4,8)->x1; v[8,12)->ffacc; ctx[12,16);
//   xb[16,20) (dead after Wo) -> ffmid[16,32).  Peak 32 MiB (proven).
// d_out first 6MB = transposed bf16 weights (LN2 overwrites at end).

#define D_MODEL 512
#define N_HEADS 8
#define D_K 64
#define D_FF 2048
#define BATCH 2
#define SEQ 2048
#define NROWS (BATCH * SEQ)

typedef __hip_bfloat16 bf16;
typedef __attribute__((ext_vector_type(8))) short bf16x8;
typedef __attribute__((ext_vector_type(4))) float f32x4;

__device__ __forceinline__ unsigned short f2b(float f) {
  union { bf16 b; unsigned short u; } cv;
  cv.b = __float2bfloat16(f);
  return cv.u;
}
__device__ __forceinline__ float b2f(unsigned short u) {
  return __uint_as_float(((unsigned int)u) << 16);
}
__device__ __forceinline__ float toF(const bf16 x) { return __bfloat162float(x); }
__device__ __forceinline__ float toF(const float x) { return x; }
__device__ __forceinline__ void storeC(float* p, float v) { *p = v; }
__device__ __forceinline__ void storeC(bf16* p, float v) {
  *p = __float2bfloat16(v);
}

__device__ __forceinline__ void ld8f(const float* p, float* v) {
  const float4 a = *(const float4*)p;
  const float4 b = *(const float4*)(p + 4);
  v[0] = a.x; v[1] = a.y; v[2] = a.z; v[3] = a.w;
  v[4] = b.x; v[5] = b.y; v[6] = b.z; v[7] = b.w;
}
__device__ __forceinline__ void ld8f(const bf16* p, float* v) {
  const bf16x8 u = *(const bf16x8*)p;
#pragma unroll
  for (int i = 0; i < 8; ++i) v[i] = b2f((unsigned short)u[i]);
}
__device__ __forceinline__ void st8f(float* p, const float* v) {
  *(float4*)p = make_float4(v[0], v[1], v[2], v[3]);
  *(float4*)(p + 4) = make_float4(v[4], v[5], v[6], v[7]);
}
__device__ __forceinline__ void st8f(bf16* p, const float* v) {
  bf16x8 u;
#pragma unroll
  for (int i = 0; i < 8; ++i) u[i] = (short)f2b(v[i]);
  *(bf16x8*)p = u;
}

// Wt element offsets inside the d_out scratch region
#define WT_Q 0
#define WT_K 262144
#define WT_V 524288
#define WT_O 786432
#define WT_1 1048576
#define WT_2 2097152

// ---------------------------------------------------------------------------
// prep: z<6: W[R][Cn] fp32 -> Wt[Cn][R] bf16 (transposed). z=6: x -> bf16.
// ---------------------------------------------------------------------------
__global__ __launch_bounds__(256) void prep_kernel(
    const float* __restrict__ Wq, const float* __restrict__ Wk,
    const float* __restrict__ Wv, const float* __restrict__ Wo,
    const float* __restrict__ W1, const float* __restrict__ W2,
    bf16* __restrict__ outw, const float* __restrict__ x,
    bf16* __restrict__ xb) {
  const int z = blockIdx.z;
  const int t = threadIdx.x;

  if (z == 6) {  // xconv
    const size_t base =
        ((size_t)(blockIdx.y * 32 + blockIdx.x) * 2048) + (size_t)t * 8;
    float v[8];
    ld8f(x + base, v);
    st8f(xb + base, v);
    return;
  }

  const float* W;
  int R, Cn;
  size_t off;
  if (z == 0)      { W = Wq; R = 512;  Cn = 512;  off = WT_Q; }
  else if (z == 1) { W = Wk; R = 512;  Cn = 512;  off = WT_K; }
  else if (z == 2) { W = Wv; R = 512;  Cn = 512;  off = WT_V; }
  else if (z == 3) { W = Wo; R = 512;  Cn = 512;  off = WT_O; }
  else if (z == 4) { W = W1; R = 512;  Cn = 2048; off = WT_1; }
  else             { W = W2; R = 2048; Cn = 512;  off = WT_2; }
  const int c0 = blockIdx.x * 64;
  const int r0 = blockIdx.y * 64;
  if (c0 >= Cn || r0 >= R) return;

  __shared__ short tile[64][72];  // [c][r]
  {
    const int r = t >> 2, cg = (t & 3) * 16;
    const float* src = &W[(size_t)(r0 + r) * Cn + c0 + cg];
#pragma unroll
    for (int i = 0; i < 4; ++i) {
      const float4 v = *(const float4*)(src + 4 * i);
      tile[cg + 4 * i + 0][r] = (short)f2b(v.x);
      tile[cg + 4 * i + 1][r] = (short)f2b(v.y);
      tile[cg + 4 * i + 2][r] = (short)f2b(v.z);
      tile[cg + 4 * i + 3][r] = (short)f2b(v.w);
    }
  }
  __syncthreads();
  {
    const int c = t >> 2, rg = (t & 3) * 16;
    short* dst = (short*)outw + off + (size_t)(c0 + c) * R + r0 + rg;
    *(bf16x8*)dst = *(const bf16x8*)&tile[c][rg];
    *(bf16x8*)(dst + 8) = *(const bf16x8*)&tile[c][rg + 8];
  }
}

// ---------------------------------------------------------------------------
// gemm_bf16<BM,RELU,RESID>: C = A @ Wt^T + bias (+ R residual, ReLU).
// A[row][k] bf16 (lda), Wt[n][k] bf16 (ldk). BN=64, BK=64, block=256.
// Register prefetch + double-buffered chunk-major LDS, 1 barrier/iter.
// LDS slot s (lane-linear): c = s>>log2(BM), row = s&(BM-1); addr = s*16B.
// Frag reads: A[(quad+4kc)*BM + row], W[(quad+4kc)*64 + row] (2-way = free).
// Grid (Nview/64, M/BM, NZ); z muxes (Wt,bias,C).
// ---------------------------------------------------------------------------
template <int BM, bool RELU, bool RESID>
__global__ __launch_bounds__(256) void gemm_bf16_kernel(
    const bf16* __restrict__ A, int lda,
    const bf16* __restrict__ Wt0, const bf16* __restrict__ Wt1,
    const bf16* __restrict__ Wt2, int ldk,
    const float* __restrict__ b0, const float* __restrict__ b1,
    const float* __restrict__ b2,
    bf16* __restrict__ C0, bf16* __restrict__ C1, bf16* __restrict__ C2,
    int ldc, int K, const bf16* __restrict__ R) {
  const bf16* Wt = (blockIdx.z == 0) ? Wt0 : (blockIdx.z == 1 ? Wt1 : Wt2);
  const float* bias = (blockIdx.z == 0) ? b0 : (blockIdx.z == 1 ? b1 : b2);
  bf16* C = (blockIdx.z == 0) ? C0 : (blockIdx.z == 1 ? C1 : C2);

  constexpr int RG = BM / 64;                  // 16-row groups per wave
  constexpr int NA = BM / 32;                  // A 16B-slots per thread
  constexpr int RSH = (BM == 64) ? 6 : 7;

  __shared__ __align__(16) short asA[2][8 * BM * 8];
  __shared__ __align__(16) short bsW[2][8 * 64 * 8];

  const int rowBase = blockIdx.y * BM;
  const int colBase = blockIdx.x * 64;
  const int t = threadIdx.x;
  const int wave = t >> 6;
  const int lane = t & 63;
  const int quad = lane >> 4;
  const int l15 = lane & 15;

  // per-thread global base pointers for each staged slot
  const short* gA[NA];
#pragma unroll
  for (int i = 0; i < NA; ++i) {
    const int s = i * 256 + t;
    const int c = s >> RSH;
    const int row = s & (BM - 1);
    gA[i] = (const short*)A + (size_t)(rowBase + row) * lda + c * 8;
  }
  const short* gW[2];
#pragma unroll
  for (int i = 0; i < 2; ++i) {
    const int s = i * 256 + t;
    const int c = s >> 6;
    const int row = s & 63;
    gW[i] = (const short*)Wt + (size_t)(colBase + row) * ldk + c * 8;
  }

  bf16x8 areg[NA], wreg[2];
#pragma unroll
  for (int i = 0; i < NA; ++i) areg[i] = *(const bf16x8*)(gA[i]);
#pragma unroll
  for (int i = 0; i < 2; ++i) wreg[i] = *(const bf16x8*)(gW[i]);

  f32x4 acc[RG][4];
#pragma unroll
  for (int i = 0; i < RG; ++i)
#pragma unroll
    for (int nt = 0; nt < 4; ++nt) acc[i][nt] = (f32x4){0.f, 0.f, 0.f, 0.f};

  int cur = 0;
  for (int k0 = 0; k0 < K; k0 += 64) {
    // commit prefetched tile k to buf[cur] (races only with iter k-2 readers,
    // fenced by iter k-1's barrier)
#pragma unroll
    for (int i = 0; i < NA; ++i)
      *(bf16x8*)&asA[cur][(i * 256 + t) * 8] = areg[i];
#pragma unroll
    for (int i = 0; i < 2; ++i)
      *(bf16x8*)&bsW[cur][(i * 256 + t) * 8] = wreg[i];

    // prefetch tile k+1 into regs (rides under this iter's MFMA)
    if (k0 + 64 < K) {
#pragma unroll
      for (int i = 0; i < NA; ++i)
        areg[i] = *(const bf16x8*)(gA[i] + k0 + 64);
#pragma unroll
      for (int i = 0; i < 2; ++i)
        wreg[i] = *(const bf16x8*)(gW[i] + k0 + 64);
    }
    __syncthreads();  // ONE barrier per iteration

#pragma unroll
    for (int kc = 0; kc < 2; ++kc) {
      bf16x8 af[RG];
#pragma unroll
      for (int i = 0; i < RG; ++i)
        af[i] = *(const bf16x8*)
            &asA[cur][((quad + 4 * kc) * BM + wave * (16 * RG) + i * 16 + l15) * 8];
#pragma unroll
      for (int nt = 0; nt < 4; ++nt) {
        const bf16x8 bfr = *(const bf16x8*)
            &bsW[cur][((quad + 4 * kc) * 64 + nt * 16 + l15) * 8];
#pragma unroll
        for (int i = 0; i < RG; ++i)
          acc[i][nt] = __builtin_amdgcn_mfma_f32_16x16x32_bf16(
              af[i], bfr, acc[i][nt], 0, 0, 0);
      }
    }
    cur ^= 1;
  }

#pragma unroll
  for (int i = 0; i < RG; ++i)
#pragma unroll
    for (int nt = 0; nt < 4; ++nt) {
      const int col = colBase + nt * 16 + l15;
#pragma unroll
      for (int r = 0; r < 4; ++r) {
        const int row = rowBase + wave * (16 * RG) + i * 16 + quad * 4 + r;
        float v = acc[i][nt][r] + bias[col];
        if (RESID) v += toF(R[(size_t)row * ldc + col]);
        if (RELU) v = fmaxf(v, 0.f);
        storeC(&C[(size_t)row * ldc + col], v);
      }
    }
}

// ---------------------------------------------------------------------------
// MFMA flash attention, RG=2 (r10, unchanged). grid (SEQ/128, B*H), block 512.
// ---------------------------------------------------------------------------
__global__ __launch_bounds__(512) void attn_mfma_kernel(
    const bf16* __restrict__ Q, const bf16* __restrict__ Km,
    const bf16* __restrict__ V, const int* __restrict__ mask,
    bf16* __restrict__ ctx) {
  const int qt = blockIdx.x;
  const int bh = blockIdx.y;
  const int b = bh >> 3;
  const int h = bh & 7;
  const int t = threadIdx.x;
  const int wave = t >> 6;
  const int half = wave >> 2;
  const int wq = wave & 3;
  const int lane = t & 63;
  const int quad = lane >> 4;
  const int l15 = lane & 15;

  __shared__ __align__(16) char smem[74240];
  auto ks = (short(*)[64][72])(smem);
  auto vt = (short(*)[64][72])(smem + 18432);
  auto pb = (short(*)[32][72])(smem + 36864);
  auto mk = (int(*)[64])(smem + 73728);
  auto mg = (float(*)[32][68])(smem);  // aliases ks/vt/pb after final barrier

  bf16x8 qf[2][2];
#pragma unroll
  for (int rg = 0; rg < 2; ++rg) {
    const short* qg = (const short*)Q +
        (size_t)(b * SEQ + qt * 128 + wq * 32 + rg * 16 + l15) * D_MODEL +
        h * D_K + quad * 8;
    qf[rg][0] = *(const bf16x8*)qg;
    qf[rg][1] = *(const bf16x8*)(qg + 32);
  }

  f32x4 of[2][4];
#pragma unroll
  for (int rg = 0; rg < 2; ++rg)
#pragma unroll
    for (int nt = 0; nt < 4; ++nt) of[rg][nt] = (f32x4){0.f, 0.f, 0.f, 0.f};
  float l_acc[2][4] = {{0.f, 0.f, 0.f, 0.f}, {0.f, 0.f, 0.f, 0.f}};

  const int hs = t >> 8;
  const int tt = t & 255;
  const int kr = tt >> 2, kc0 = (tt & 3) * 16;
  const int vk = tt & 63, vc0 = ((tt >> 6) & 3) * 16;

  bf16x8 kv0, kv1, vv0, vv1;
  int mv = 1;
  {
    const int keyRow = (hs * 16 + 0) * 64;
    const short* kg = (const short*)Km +
        (size_t)(b * SEQ + keyRow + kr) * D_MODEL + h * D_K + kc0;
    kv0 = *(const bf16x8*)kg;
    kv1 = *(const bf16x8*)(kg + 8);
    const short* vg = (const short*)V +
        (size_t)(b * SEQ + keyRow + vk) * D_MODEL + h * D_K + vc0;
    vv0 = *(const bf16x8*)vg;
    vv1 = *(const bf16x8*)(vg + 8);
    if (tt < 64) mv = mask[b * SEQ + keyRow + tt];
  }

  for (int kt = 0; kt < 16; ++kt) {
    *(bf16x8*)&ks[hs][kr][kc0] = kv0;
    *(bf16x8*)&ks[hs][kr][kc0 + 8] = kv1;
#pragma unroll
    for (int i = 0; i < 8; ++i) vt[hs][vc0 + i][vk] = vv0[i];
#pragma unroll
    for (int i = 0; i < 8; ++i) vt[hs][vc0 + 8 + i][vk] = vv1[i];
    if (tt < 64) mk[hs][tt] = mv;

    if (kt + 1 < 16) {
      const int keyRow = (hs * 16 + kt + 1) * 64;
      const short* kg = (const short*)Km +
          (size_t)(b * SEQ + keyRow + kr) * D_MODEL + h * D_K + kc0;
      kv0 = *(const bf16x8*)kg;
      kv1 = *(const bf16x8*)(kg + 8);
      const short* vg = (const short*)V +
          (size_t)(b * SEQ + keyRow + vk) * D_MODEL + h * D_K + vc0;
      vv0 = *(const bf16x8*)vg;
      vv1 = *(const bf16x8*)(vg + 8);
      if (tt < 64) mv = mask[b * SEQ + keyRow + tt];
    }
    __syncthreads();

    f32x4 sf[2][4];
#pragma unroll
    for (int nt = 0; nt < 4; ++nt) {
      const bf16x8 kf0 = *(const bf16x8*)&ks[half][l15 + 16 * nt][quad * 8];
      const bf16x8 kf1 =
          *(const bf16x8*)&ks[half][l15 + 16 * nt][quad * 8 + 32];
#pragma unroll
      for (int rg = 0; rg < 2; ++rg) {
        f32x4 acc = (f32x4){0.f, 0.f, 0.f, 0.f};
        acc = __builtin_amdgcn_mfma_f32_16x16x32_bf16(qf[rg][0], kf0, acc, 0, 0, 0);
        acc = __builtin_amdgcn_mfma_f32_16x16x32_bf16(qf[rg][1], kf1, acc, 0, 0, 0);
        sf[rg][nt] = acc;
      }
    }

#pragma unroll
    for (int nt = 0; nt < 4; ++nt) {
      const bool dead = (mk[half][l15 + 16 * nt] == 0);
#pragma unroll
      for (int rg = 0; rg < 2; ++rg)
#pragma unroll
        for (int r = 0; r < 4; ++r) {
          float p = __expf(fmaf(sf[rg][nt][r], 0.125f, -8.f));
          if (dead) p = 0.f;
          l_acc[rg][r] += p;
          pb[wave][rg * 16 + quad * 4 + r][l15 + 16 * nt] = (short)f2b(p);
        }
    }

#pragma unroll
    for (int kc = 0; kc < 2; ++kc) {
      bf16x8 pf[2];
#pragma unroll
      for (int rg = 0; rg < 2; ++rg)
        pf[rg] = *(const bf16x8*)&pb[wave][rg * 16 + l15][kc * 32 + quad * 8];
#pragma unroll
      for (int nt = 0; nt < 4; ++nt) {
        const bf16x8 vf =
            *(const bf16x8*)&vt[half][l15 + 16 * nt][kc * 32 + quad * 8];
#pragma unroll
        for (int rg = 0; rg < 2; ++rg)
          of[rg][nt] = __builtin_amdgcn_mfma_f32_16x16x32_bf16(
              pf[rg], vf, of[rg][nt], 0, 0, 0);
      }
    }
    __syncthreads();
  }

#pragma unroll
  for (int xm = 1; xm < 16; xm <<= 1)
#pragma unroll
    for (int rg = 0; rg < 2; ++rg)
#pragma unroll
      for (int r = 0; r < 4; ++r)
        l_acc[rg][r] += __shfl_xor(l_acc[rg][r], xm, 64);

#pragma unroll
  for (int rg = 0; rg < 2; ++rg)
#pragma unroll
    for (int nt = 0; nt < 4; ++nt)
#pragma unroll
      for (int r = 0; r < 4; ++r)
        mg[wave][rg * 16 + quad * 4 + r][l15 + 16 * nt] = of[rg][nt][r];
  if (l15 == 0) {
#pragma unroll
    for (int rg = 0; rg < 2; ++rg)
#pragma unroll
      for (int r = 0; r < 4; ++r)
        mg[wave][rg * 16 + quad * 4 + r][64] = l_acc[rg][r];
  }
  __syncthreads();

  if (wave < 4) {
    const int pw = wave + 4;
#pragma unroll
    for (int rg = 0; rg < 2; ++rg)
#pragma unroll
      for (int r = 0; r < 4; ++r) {
        const int qrow = rg * 16 + quad * 4 + r;
        const float inv = 1.f / (l_acc[rg][r] + mg[pw][qrow][64]);
        const int row = qt * 128 + wave * 32 + qrow;
        bf16* cp = ctx + (size_t)(b * SEQ + row) * D_MODEL + h * D_K;
#pragma unroll
        for (int nt = 0; nt < 4; ++nt)
          cp[l15 + 16 * nt] = __float2bfloat16(
              (of[rg][nt][r] + mg[pw][qrow][l15 + 16 * nt]) * inv);
      }
  }
}

// ---------------------------------------------------------------------------
// Wave-per-row LayerNorm (single input): out = LN(base)*g+beta.
// block 256 = 4 rows, grid NROWS/4. Shfl butterfly only.
// ---------------------------------------------------------------------------
template <typename BT, typename OT>
__global__ __launch_bounds__(256) void ln_kernel(
    const BT* __restrict__ base, const float* __restrict__ g,
    const float* __restrict__ beta, OT* __restrict__ out) {
  const int wave = threadIdx.x >> 6;
  const int lane = threadIdx.x & 63;
  const int row = blockIdx.x * 4 + wave;
  const size_t rb = (size_t)row * D_MODEL + lane * 8;

  float v[8];
  ld8f(base + rb, v);

  float s = 0.f;
#pragma unroll
  for (int i = 0; i < 8; ++i) s += v[i];
#pragma unroll
  for (int xm = 1; xm < 64; xm <<= 1) s += __shfl_xor(s, xm, 64);
  const float mu = s * (1.f / (float)D_MODEL);

  float q = 0.f;
#pragma unroll
  for (int i = 0; i < 8; ++i) {
    v[i] -= mu;
    q += v[i] * v[i];
  }
#pragma unroll
  for (int xm = 1; xm < 64; xm <<= 1) q += __shfl_xor(q, xm, 64);
  const float rs = rsqrtf(q * (1.f / (float)D_MODEL) + 1e-5f);

  float gv[8], bv[8];
  ld8f(g + lane * 8, gv);
  ld8f(beta + lane * 8, bv);
#pragma unroll
  for (int i = 0; i < 8; ++i) v[i] = v[i] * rs * gv[i] + bv[i];
  st8f(out + rb, v);
}

// ---------------------------------------------------------------------------
extern "C" void kernel_launch(void* const* d_in, const int* in_sizes, int n_in,
                              void* d_out, int out_size, void* d_ws, size_t ws_size,
                              hipStream_t stream) {
  const float* x     = (const float*)d_in[0];
  const int*   mask  = (const int*)d_in[1];
  const float* Wq    = (const float*)d_in[2];
  const float* bq    = (const float*)d_in[3];
  const float* Wk    = (const float*)d_in[4];
  const float* bk    = (const float*)d_in[5];
  const float* Wv    = (const float*)d_in[6];
  const float* bv    = (const float*)d_in[7];
  const float* Wo    = (const float*)d_in[8];
  const float* bo    = (const float*)d_in[9];
  const float* W1    = (const float*)d_in[10];
  const float* b1    = (const float*)d_in[11];
  const float* W2    = (const float*)d_in[12];
  const float* b2    = (const float*)d_in[13];
  const float* g1    = (const float*)d_in[14];
  const float* beta1 = (const float*)d_in[15];
  const float* g2    = (const float*)d_in[16];
  const float* beta2 = (const float*)d_in[17];
  float* out = (float*)d_out;

  char* ws = (char*)d_ws;
  const size_t MB4 = (size_t)NROWS * D_MODEL * sizeof(bf16);  // 4 MiB
  bf16* q        = (bf16*)(ws + 0 * MB4);
  bf16* kbuf     = (bf16*)(ws + 1 * MB4);
  bf16* vbuf     = (bf16*)(ws + 2 * MB4);
  bf16* ctx      = (bf16*)(ws + 3 * MB4);
  bf16* xb       = (bf16*)(ws + 4 * MB4);  // [16,20), dead after Wo
  bf16* attn_out = q;                      // q dead after attention
  bf16* x1       = kbuf;                   // k dead after attention
  bf16* ffacc    = vbuf;                   // v dead after attention
  bf16* ffmid    = (bf16*)(ws + 4 * MB4);  // [16,32), xb dead after Wo

  bf16* wt = (bf16*)d_out;  // 6MB transposed bf16 weights (LN2 overwrites)

  const dim3 blk(256);

  // prep: weights -> bf16 transposed; x -> bf16 (z=6)
  prep_kernel<<<dim3(32, 32, 7), blk, 0, stream>>>(Wq, Wk, Wv, Wo, W1, W2, wt,
                                                   x, xb);

  // QKV fused, BM=128
  gemm_bf16_kernel<128, false, false>
      <<<dim3(D_MODEL / 64, NROWS / 128, 3), blk, 0, stream>>>(
          xb, D_MODEL, wt + WT_Q, wt + WT_K, wt + WT_V, D_MODEL,
          bq, bk, bv, q, kbuf, vbuf, D_MODEL, D_MODEL, nullptr);

  // attention (RG=2: 128 q rows per block)
  attn_mfma_kernel<<<dim3(SEQ / 128, BATCH * N_HEADS), dim3(512), 0, stream>>>(
      q, kbuf, vbuf, mask, ctx);

  // Wo projection + residual (xb): attn_out = ctx@Wo + bo + x
  gemm_bf16_kernel<64, false, true>
      <<<dim3(D_MODEL / 64, NROWS / 64, 1), blk, 0, stream>>>(
          ctx, D_MODEL, wt + WT_O, wt + WT_O, wt + WT_O, D_MODEL,
          bo, bo, bo, attn_out, attn_out, attn_out, D_MODEL, D_MODEL, xb);

  // LN1: x1 = LN(attn_out) -> bf16
  ln_kernel<bf16, bf16><<<NROWS / 4, blk, 0, stream>>>(attn_out, g1, beta1, x1);

  // FF1 single launch: ffmid = relu(x1 @ W1 + b1), N=2048
  gemm_bf16_kernel<128, true, false>
      <<<dim3(D_FF / 64, NROWS / 128, 1), blk, 0, stream>>>(
          x1, D_MODEL, wt + WT_1, wt + WT_1, wt + WT_1, D_MODEL,
          b1, b1, b1, ffmid, ffmid, ffmid, D_FF, D_MODEL, nullptr);

  // FF2 single launch (K=2048) + residual (x1): ffacc = ffmid@W2 + b2 + x1
  gemm_bf16_kernel<64, false, true>
      <<<dim3(D_MODEL / 64, NROWS / 64, 1), blk, 0, stream>>>(
          ffmid, D_FF, wt + WT_2, wt + WT_2, wt + WT_2, D_FF,
          b2, b2, b2, ffacc, ffacc, ffacc, D_MODEL, D_FF, x1);

  // LN2 -> fp32 output (overwrites wt scratch)
  ln_kernel<bf16, float><<<NROWS / 4, blk, 0, stream>>>(ffacc, g2, beta2, out);
}

// Round 13
// 241.003 us; speedup vs baseline: 1.0221x; 1.0221x over previous
//
#include <hip/hip_runtime.h>
#include <hip/hip_bf16.h>

// EncoderLayer: B=2, S=2048, D_MODEL=512, H=8, D_FF=2048
// Round 13: fix the GEMM pipeline barrier placement. r10/r12 issued the
// register prefetch BEFORE __syncthreads -> the barrier's vmcnt(0) drained it
// (prefetch never overlapped MFMA; global latency naked every iter).
// New order: barrier -> prefetch(k+1) -> MFMA(buf k&1) -> ds_write buf[(k+1)&1]
// (implicit vmcnt wait lands after MFMA). One barrier/iter, double-buffered
// chunk-major LDS (r12-proven layout, uniform 8 req/bank).
// Attention (r10, 44us), prep, LN unchanged.
// ws (MiB): q[0,4)->attn_out; k[4,8)->x1; v[8,12)->ffacc; ctx[12,16);
//   xb[16,20) (dead after Wo) -> ffmid[16,32).  Peak 32 MiB (proven).
// d_out first 6MB = transposed bf16 weights (LN2 overwrites at end).

#define D_MODEL 512
#define N_HEADS 8
#define D_K 64
#define D_FF 2048
#define BATCH 2
#define SEQ 2048
#define NROWS (BATCH * SEQ)

typedef __hip_bfloat16 bf16;
typedef __attribute__((ext_vector_type(8))) short bf16x8;
typedef __attribute__((ext_vector_type(4))) float f32x4;

__device__ __forceinline__ unsigned short f2b(float f) {
  union { bf16 b; unsigned short u; } cv;
  cv.b = __float2bfloat16(f);
  return cv.u;
}
__device__ __forceinline__ float b2f(unsigned short u) {
  return __uint_as_float(((unsigned int)u) << 16);
}
__device__ __forceinline__ float toF(const bf16 x) { return __bfloat162float(x); }
__device__ __forceinline__ float toF(const float x) { return x; }
__device__ __forceinline__ void storeC(float* p, float v) { *p = v; }
__device__ __forceinline__ void storeC(bf16* p, float v) {
  *p = __float2bfloat16(v);
}

__device__ __forceinline__ void ld8f(const float* p, float* v) {
  const float4 a = *(const float4*)p;
  const float4 b = *(const float4*)(p + 4);
  v[0] = a.x; v[1] = a.y; v[2] = a.z; v[3] = a.w;
  v[4] = b.x; v[5] = b.y; v[6] = b.z; v[7] = b.w;
}
__device__ __forceinline__ void ld8f(const bf16* p, float* v) {
  const bf16x8 u = *(const bf16x8*)p;
#pragma unroll
  for (int i = 0; i < 8; ++i) v[i] = b2f((unsigned short)u[i]);
}
__device__ __forceinline__ void st8f(float* p, const float* v) {
  *(float4*)p = make_float4(v[0], v[1], v[2], v[3]);
  *(float4*)(p + 4) = make_float4(v[4], v[5], v[6], v[7]);
}
__device__ __forceinline__ void st8f(bf16* p, const float* v) {
  bf16x8 u;
#pragma unroll
  for (int i = 0; i < 8; ++i) u[i] = (short)f2b(v[i]);
  *(bf16x8*)p = u;
}

// Wt element offsets inside the d_out scratch region
#define WT_Q 0
#define WT_K 262144
#define WT_V 524288
#define WT_O 786432
#define WT_1 1048576
#define WT_2 2097152

// ---------------------------------------------------------------------------
// prep: z<6: W[R][Cn] fp32 -> Wt[Cn][R] bf16 (transposed). z=6: x -> bf16.
// ---------------------------------------------------------------------------
__global__ __launch_bounds__(256) void prep_kernel(
    const float* __restrict__ Wq, const float* __restrict__ Wk,
    const float* __restrict__ Wv, const float* __restrict__ Wo,
    const float* __restrict__ W1, const float* __restrict__ W2,
    bf16* __restrict__ outw, const float* __restrict__ x,
    bf16* __restrict__ xb) {
  const int z = blockIdx.z;
  const int t = threadIdx.x;

  if (z == 6) {  // xconv
    const size_t base =
        ((size_t)(blockIdx.y * 32 + blockIdx.x) * 2048) + (size_t)t * 8;
    float v[8];
    ld8f(x + base, v);
    st8f(xb + base, v);
    return;
  }

  const float* W;
  int R, Cn;
  size_t off;
  if (z == 0)      { W = Wq; R = 512;  Cn = 512;  off = WT_Q; }
  else if (z == 1) { W = Wk; R = 512;  Cn = 512;  off = WT_K; }
  else if (z == 2) { W = Wv; R = 512;  Cn = 512;  off = WT_V; }
  else if (z == 3) { W = Wo; R = 512;  Cn = 512;  off = WT_O; }
  else if (z == 4) { W = W1; R = 512;  Cn = 2048; off = WT_1; }
  else             { W = W2; R = 2048; Cn = 512;  off = WT_2; }
  const int c0 = blockIdx.x * 64;
  const int r0 = blockIdx.y * 64;
  if (c0 >= Cn || r0 >= R) return;

  __shared__ short tile[64][72];  // [c][r]
  {
    const int r = t >> 2, cg = (t & 3) * 16;
    const float* src = &W[(size_t)(r0 + r) * Cn + c0 + cg];
#pragma unroll
    for (int i = 0; i < 4; ++i) {
      const float4 v = *(const float4*)(src + 4 * i);
      tile[cg + 4 * i + 0][r] = (short)f2b(v.x);
      tile[cg + 4 * i + 1][r] = (short)f2b(v.y);
      tile[cg + 4 * i + 2][r] = (short)f2b(v.z);
      tile[cg + 4 * i + 3][r] = (short)f2b(v.w);
    }
  }
  __syncthreads();
  {
    const int c = t >> 2, rg = (t & 3) * 16;
    short* dst = (short*)outw + off + (size_t)(c0 + c) * R + r0 + rg;
    *(bf16x8*)dst = *(const bf16x8*)&tile[c][rg];
    *(bf16x8*)(dst + 8) = *(const bf16x8*)&tile[c][rg + 8];
  }
}

// ---------------------------------------------------------------------------
// gemm_bf16<BM,RELU,RESID>: C = A @ Wt^T + bias (+ R residual, ReLU).
// A[row][k] bf16 (lda), Wt[n][k] bf16 (ldk). BN=64, BK=64, block=256.
// Pipelined: barrier -> prefetch(k+1) -> MFMA(buf[k&1]) -> write buf[(k+1)&1].
// Chunk-major LDS: slot s -> addr s*16B; c = s>>log2(BM), row = s&(BM-1).
// Grid (Nview/64, M/BM, NZ); z muxes (Wt,bias,C).
// ---------------------------------------------------------------------------
template <int BM, bool RELU, bool RESID>
__global__ __launch_bounds__(256) void gemm_bf16_kernel(
    const bf16* __restrict__ A, int lda,
    const bf16* __restrict__ Wt0, const bf16* __restrict__ Wt1,
    const bf16* __restrict__ Wt2, int ldk,
    const float* __restrict__ b0, const float* __restrict__ b1,
    const float* __restrict__ b2,
    bf16* __restrict__ C0, bf16* __restrict__ C1, bf16* __restrict__ C2,
    int ldc, int K, const bf16* __restrict__ R) {
  const bf16* Wt = (blockIdx.z == 0) ? Wt0 : (blockIdx.z == 1 ? Wt1 : Wt2);
  const float* bias = (blockIdx.z == 0) ? b0 : (blockIdx.z == 1 ? b1 : b2);
  bf16* C = (blockIdx.z == 0) ? C0 : (blockIdx.z == 1 ? C1 : C2);

  constexpr int RG = BM / 64;                  // 16-row groups per wave
  constexpr int NA = BM / 32;                  // A 16B-slots per thread
  constexpr int RSH = (BM == 64) ? 6 : 7;

  __shared__ __align__(16) short asA[2][8 * BM * 8];
  __shared__ __align__(16) short bsW[2][8 * 64 * 8];

  const int rowBase = blockIdx.y * BM;
  const int colBase = blockIdx.x * 64;
  const int t = threadIdx.x;
  const int wave = t >> 6;
  const int lane = t & 63;
  const int quad = lane >> 4;
  const int l15 = lane & 15;

  // per-thread global base pointers for each staged slot
  const short* gA[NA];
#pragma unroll
  for (int i = 0; i < NA; ++i) {
    const int s = i * 256 + t;
    const int c = s >> RSH;
    const int row = s & (BM - 1);
    gA[i] = (const short*)A + (size_t)(rowBase + row) * lda + c * 8;
  }
  const short* gW[2];
#pragma unroll
  for (int i = 0; i < 2; ++i) {
    const int s = i * 256 + t;
    const int c = s >> 6;
    const int row = s & 63;
    gW[i] = (const short*)Wt + (size_t)(colBase + row) * ldk + c * 8;
  }

  f32x4 acc[RG][4];
#pragma unroll
  for (int i = 0; i < RG; ++i)
#pragma unroll
    for (int nt = 0; nt < 4; ++nt) acc[i][nt] = (f32x4){0.f, 0.f, 0.f, 0.f};

  // pre-loop: load + commit tile 0 into buf 0 (vmcnt wait is natural here)
  {
    bf16x8 a0[NA], w0[2];
#pragma unroll
    for (int i = 0; i < NA; ++i) a0[i] = *(const bf16x8*)(gA[i]);
#pragma unroll
    for (int i = 0; i < 2; ++i) w0[i] = *(const bf16x8*)(gW[i]);
#pragma unroll
    for (int i = 0; i < NA; ++i)
      *(bf16x8*)&asA[0][(i * 256 + t) * 8] = a0[i];
#pragma unroll
    for (int i = 0; i < 2; ++i)
      *(bf16x8*)&bsW[0][(i * 256 + t) * 8] = w0[i];
  }

  const int nIter = K >> 6;
  bf16x8 areg[NA], wreg[2];

  for (int k = 0; k < nIter; ++k) {
    const int cur = k & 1;
    __syncthreads();  // fences prev iter's write of buf[cur] vs this read

    // prefetch tile k+1 AFTER the barrier: stays in flight through MFMA
    if (k + 1 < nIter) {
      const int ko = (k + 1) * 64;
#pragma unroll
      for (int i = 0; i < NA; ++i) areg[i] = *(const bf16x8*)(gA[i] + ko);
#pragma unroll
      for (int i = 0; i < 2; ++i) wreg[i] = *(const bf16x8*)(gW[i] + ko);
    }

    // MFMA phase on buf[cur]
#pragma unroll
    for (int kc = 0; kc < 2; ++kc) {
      bf16x8 af[RG];
#pragma unroll
      for (int i = 0; i < RG; ++i)
        af[i] = *(const bf16x8*)
            &asA[cur][((quad + 4 * kc) * BM + wave * (16 * RG) + i * 16 + l15) * 8];
#pragma unroll
      for (int nt = 0; nt < 4; ++nt) {
        const bf16x8 bfr = *(const bf16x8*)
            &bsW[cur][((quad + 4 * kc) * 64 + nt * 16 + l15) * 8];
#pragma unroll
        for (int i = 0; i < RG; ++i)
          acc[i][nt] = __builtin_amdgcn_mfma_f32_16x16x32_bf16(
              af[i], bfr, acc[i][nt], 0, 0, 0);
      }
    }

    // commit prefetched tile to the other buffer (vmcnt wait lands here,
    // AFTER the MFMA phase; safe vs readers via the next barrier)
    if (k + 1 < nIter) {
      const int nxt = cur ^ 1;
#pragma unroll
      for (int i = 0; i < NA; ++i)
        *(bf16x8*)&asA[nxt][(i * 256 + t) * 8] = areg[i];
#pragma unroll
      for (int i = 0; i < 2; ++i)
        *(bf16x8*)&bsW[nxt][(i * 256 + t) * 8] = wreg[i];
    }
  }

#pragma unroll
  for (int i = 0; i < RG; ++i)
#pragma unroll
    for (int nt = 0; nt < 4; ++nt) {
      const int col = colBase + nt * 16 + l15;
#pragma unroll
      for (int r = 0; r < 4; ++r) {
        const int row = rowBase + wave * (16 * RG) + i * 16 + quad * 4 + r;
        float v = acc[i][nt][r] + bias[col];
        if (RESID) v += toF(R[(size_t)row * ldc + col]);
        if (RELU) v = fmaxf(v, 0.f);
        storeC(&C[(size_t)row * ldc + col], v);
      }
    }
}

// ---------------------------------------------------------------------------
// MFMA flash attention, RG=2 (r10, unchanged). grid (SEQ/128, B*H), block 512.
// ---------------------------------------------------------------------------
__global__ __launch_bounds__(512) void attn_mfma_kernel(
    const bf16* __restrict__ Q, const bf16* __restrict__ Km,
    const bf16* __restrict__ V, const int* __restrict__ mask,
    bf16* __restrict__ ctx) {
  const int qt = blockIdx.x;
  const int bh = blockIdx.y;
  const int b = bh >> 3;
  const int h = bh & 7;
  const int t = threadIdx.x;
  const int wave = t >> 6;
  const int half = wave >> 2;
  const int wq = wave & 3;
  const int lane = t & 63;
  const int quad = lane >> 4;
  const int l15 = lane & 15;

  __shared__ __align__(16) char smem[74240];
  auto ks = (short(*)[64][72])(smem);
  auto vt = (short(*)[64][72])(smem + 18432);
  auto pb = (short(*)[32][72])(smem + 36864);
  auto mk = (int(*)[64])(smem + 73728);
  auto mg = (float(*)[32][68])(smem);  // aliases ks/vt/pb after final barrier

  bf16x8 qf[2][2];
#pragma unroll
  for (int rg = 0; rg < 2; ++rg) {
    const short* qg = (const short*)Q +
        (size_t)(b * SEQ + qt * 128 + wq * 32 + rg * 16 + l15) * D_MODEL +
        h * D_K + quad * 8;
    qf[rg][0] = *(const bf16x8*)qg;
    qf[rg][1] = *(const bf16x8*)(qg + 32);
  }

  f32x4 of[2][4];
#pragma unroll
  for (int rg = 0; rg < 2; ++rg)
#pragma unroll
    for (int nt = 0; nt < 4; ++nt) of[rg][nt] = (f32x4){0.f, 0.f, 0.f, 0.f};
  float l_acc[2][4] = {{0.f, 0.f, 0.f, 0.f}, {0.f, 0.f, 0.f, 0.f}};

  const int hs = t >> 8;
  const int tt = t & 255;
  const int kr = tt >> 2, kc0 = (tt & 3) * 16;
  const int vk = tt & 63, vc0 = ((tt >> 6) & 3) * 16;

  bf16x8 kv0, kv1, vv0, vv1;
  int mv = 1;
  {
    const int keyRow = (hs * 16 + 0) * 64;
    const short* kg = (const short*)Km +
        (size_t)(b * SEQ + keyRow + kr) * D_MODEL + h * D_K + kc0;
    kv0 = *(const bf16x8*)kg;
    kv1 = *(const bf16x8*)(kg + 8);
    const short* vg = (const short*)V +
        (size_t)(b * SEQ + keyRow + vk) * D_MODEL + h * D_K + vc0;
    vv0 = *(const bf16x8*)vg;
    vv1 = *(const bf16x8*)(vg + 8);
    if (tt < 64) mv = mask[b * SEQ + keyRow + tt];
  }

  for (int kt = 0; kt < 16; ++kt) {
    *(bf16x8*)&ks[hs][kr][kc0] = kv0;
    *(bf16x8*)&ks[hs][kr][kc0 + 8] = kv1;
#pragma unroll
    for (int i = 0; i < 8; ++i) vt[hs][vc0 + i][vk] = vv0[i];
#pragma unroll
    for (int i = 0; i < 8; ++i) vt[hs][vc0 + 8 + i][vk] = vv1[i];
    if (tt < 64) mk[hs][tt] = mv;

    if (kt + 1 < 16) {
      const int keyRow = (hs * 16 + kt + 1) * 64;
      const short* kg = (const short*)Km +
          (size_t)(b * SEQ + keyRow + kr) * D_MODEL + h * D_K + kc0;
      kv0 = *(const bf16x8*)kg;
      kv1 = *(const bf16x8*)(kg + 8);
      const short* vg = (const short*)V +
          (size_t)(b * SEQ + keyRow + vk) * D_MODEL + h * D_K + vc0;
      vv0 = *(const bf16x8*)vg;
      vv1 = *(const bf16x8*)(vg + 8);
      if (tt < 64) mv = mask[b * SEQ + keyRow + tt];
    }
    __syncthreads();

    f32x4 sf[2][4];
#pragma unroll
    for (int nt = 0; nt < 4; ++nt) {
      const bf16x8 kf0 = *(const bf16x8*)&ks[half][l15 + 16 * nt][quad * 8];
      const bf16x8 kf1 =
          *(const bf16x8*)&ks[half][l15 + 16 * nt][quad * 8 + 32];
#pragma unroll
      for (int rg = 0; rg < 2; ++rg) {
        f32x4 acc = (f32x4){0.f, 0.f, 0.f, 0.f};
        acc = __builtin_amdgcn_mfma_f32_16x16x32_bf16(qf[rg][0], kf0, acc, 0, 0, 0);
        acc = __builtin_amdgcn_mfma_f32_16x16x32_bf16(qf[rg][1], kf1, acc, 0, 0, 0);
        sf[rg][nt] = acc;
      }
    }

#pragma unroll
    for (int nt = 0; nt < 4; ++nt) {
      const bool dead = (mk[half][l15 + 16 * nt] == 0);
#pragma unroll
      for (int rg = 0; rg < 2; ++rg)
#pragma unroll
        for (int r = 0; r < 4; ++r) {
          float p = __expf(fmaf(sf[rg][nt][r], 0.125f, -8.f));
          if (dead) p = 0.f;
          l_acc[rg][r] += p;
          pb[wave][rg * 16 + quad * 4 + r][l15 + 16 * nt] = (short)f2b(p);
        }
    }

#pragma unroll
    for (int kc = 0; kc < 2; ++kc) {
      bf16x8 pf[2];
#pragma unroll
      for (int rg = 0; rg < 2; ++rg)
        pf[rg] = *(const bf16x8*)&pb[wave][rg * 16 + l15][kc * 32 + quad * 8];
#pragma unroll
      for (int nt = 0; nt < 4; ++nt) {
        const bf16x8 vf =
            *(const bf16x8*)&vt[half][l15 + 16 * nt][kc * 32 + quad * 8];
#pragma unroll
        for (int rg = 0; rg < 2; ++rg)
          of[rg][nt] = __builtin_amdgcn_mfma_f32_16x16x32_bf16(
              pf[rg], vf, of[rg][nt], 0, 0, 0);
      }
    }
    __syncthreads();
  }

#pragma unroll
  for (int xm = 1; xm < 16; xm <<= 1)
#pragma unroll
    for (int rg = 0; rg < 2; ++rg)
#pragma unroll
      for (int r = 0; r < 4; ++r)
        l_acc[rg][r] += __shfl_xor(l_acc[rg][r], xm, 64);

#pragma unroll
  for (int rg = 0; rg < 2; ++rg)
#pragma unroll
    for (int nt = 0; nt < 4; ++nt)
#pragma unroll
      for (int r = 0; r < 4; ++r)
        mg[wave][rg * 16 + quad * 4 + r][l15 + 16 * nt] = of[rg][nt][r];
  if (l15 == 0) {
#pragma unroll
    for (int rg = 0; rg < 2; ++rg)
#pragma unroll
      for (int r = 0; r < 4; ++r)
        mg[wave][rg * 16 + quad * 4 + r][64] = l_acc[rg][r];
  }
  __syncthreads();

  if (wave < 4) {
    const int pw = wave + 4;
#pragma unroll
    for (int rg = 0; rg < 2; ++rg)
#pragma unroll
      for (int r = 0; r < 4; ++r) {
        const int qrow = rg * 16 + quad * 4 + r;
        const float inv = 1.f / (l_acc[rg][r] + mg[pw][qrow][64]);
        const int row = qt * 128 + wave * 32 + qrow;
        bf16* cp = ctx + (size_t)(b * SEQ + row) * D_MODEL + h * D_K;
#pragma unroll
        for (int nt = 0; nt < 4; ++nt)
          cp[l15 + 16 * nt] = __float2bfloat16(
              (of[rg][nt][r] + mg[pw][qrow][l15 + 16 * nt]) * inv);
      }
  }
}

// ---------------------------------------------------------------------------
// Wave-per-row LayerNorm (single input): out = LN(base)*g+beta.
// block 256 = 4 rows, grid NROWS/4. Shfl butterfly only.
// ---------------------------------------------------------------------------
template <typename BT, typename OT>
__global__ __launch_bounds__(256) void ln_kernel(
    const BT* __restrict__ base, const float* __restrict__ g,
    const float* __restrict__ beta, OT* __restrict__ out) {
  const int wave = threadIdx.x >> 6;
  const int lane = threadIdx.x & 63;
  const int row = blockIdx.x * 4 + wave;
  const size_t rb = (size_t)row * D_MODEL + lane * 8;

  float v[8];
  ld8f(base + rb, v);

  float s = 0.f;
#pragma unroll
  for (int i = 0; i < 8; ++i) s += v[i];
#pragma unroll
  for (int xm = 1; xm < 64; xm <<= 1) s += __shfl_xor(s, xm, 64);
  const float mu = s * (1.f / (float)D_MODEL);

  float q = 0.f;
#pragma unroll
  for (int i = 0; i < 8; ++i) {
    v[i] -= mu;
    q += v[i] * v[i];
  }
#pragma unroll
  for (int xm = 1; xm < 64; xm <<= 1) q += __shfl_xor(q, xm, 64);
  const float rs = rsqrtf(q * (1.f / (float)D_MODEL) + 1e-5f);

  float gv[8], bv[8];
  ld8f(g + lane * 8, gv);
  ld8f(beta + lane * 8, bv);
#pragma unroll
  for (int i = 0; i < 8; ++i) v[i] = v[i] * rs * gv[i] + bv[i];
  st8f(out + rb, v);
}

// ---------------------------------------------------------------------------
extern "C" void kernel_launch(void* const* d_in, const int* in_sizes, int n_in,
                              void* d_out, int out_size, void* d_ws, size_t ws_size,
                              hipStream_t stream) {
  const float* x     = (const float*)d_in[0];
  const int*   mask  = (const int*)d_in[1];
  const float* Wq    = (const float*)d_in[2];
  const float* bq    = (const float*)d_in[3];
  const float* Wk    = (const float*)d_in[4];
  const float* bk    = (const float*)d_in[5];
  const float* Wv    = (const float*)d_in[6];
  const float* bv    = (const float*)d_in[7];
  const float* Wo    = (const float*)d_in[8];
  const float* bo    = (const float*)d_in[9];
  const float* W1    = (const float*)d_in[10];
  const float* b1    = (const float*)d_in[11];
  const float* W2    = (const float*)d_in[12];
  const float* b2    = (const float*)d_in[13];
  const float* g1    = (const float*)d_in[14];
  const float* beta1 = (const float*)d_in[15];
  const float* g2    = (const float*)d_in[16];
  const float* beta2 = (const float*)d_in[17];
  float* out = (float*)d_out;

  char* ws = (char*)d_ws;
  const size_t MB4 = (size_t)NROWS * D_MODEL * sizeof(bf16);  // 4 MiB
  bf16* q        = (bf16*)(ws + 0 * MB4);
  bf16* kbuf     = (bf16*)(ws + 1 * MB4);
  bf16* vbuf     = (bf16*)(ws + 2 * MB4);
  bf16* ctx      = (bf16*)(ws + 3 * MB4);
  bf16* xb       = (bf16*)(ws + 4 * MB4);  // [16,20), dead after Wo
  bf16* attn_out = q;                      // q dead after attention
  bf16* x1       = kbuf;                   // k dead after attention
  bf16* ffacc    = vbuf;                   // v dead after attention
  bf16* ffmid    = (bf16*)(ws + 4 * MB4);  // [16,32), xb dead after Wo

  bf16* wt = (bf16*)d_out;  // 6MB transposed bf16 weights (LN2 overwrites)

  const dim3 blk(256);

  // prep: weights -> bf16 transposed; x -> bf16 (z=6)
  prep_kernel<<<dim3(32, 32, 7), blk, 0, stream>>>(Wq, Wk, Wv, Wo, W1, W2, wt,
                                                   x, xb);

  // QKV fused, BM=128
  gemm_bf16_kernel<128, false, false>
      <<<dim3(D_MODEL / 64, NROWS / 128, 3), blk, 0, stream>>>(
          xb, D_MODEL, wt + WT_Q, wt + WT_K, wt + WT_V, D_MODEL,
          bq, bk, bv, q, kbuf, vbuf, D_MODEL, D_MODEL, nullptr);

  // attention (RG=2: 128 q rows per block)
  attn_mfma_kernel<<<dim3(SEQ / 128, BATCH * N_HEADS), dim3(512), 0, stream>>>(
      q, kbuf, vbuf, mask, ctx);

  // Wo projection + residual (xb): attn_out = ctx@Wo + bo + x
  gemm_bf16_kernel<64, false, true>
      <<<dim3(D_MODEL / 64, NROWS / 64, 1), blk, 0, stream>>>(
          ctx, D_MODEL, wt + WT_O, wt + WT_O, wt + WT_O, D_MODEL,
          bo, bo, bo, attn_out, attn_out, attn_out, D_MODEL, D_MODEL, xb);

  // LN1: x1 = LN(attn_out) -> bf16
  ln_kernel<bf16, bf16><<<NROWS / 4, blk, 0, stream>>>(attn_out, g1, beta1, x1);

  // FF1 single launch: ffmid = relu(x1 @ W1 + b1), N=2048
  gemm_bf16_kernel<128, true, false>
      <<<dim3(D_FF / 64, NROWS / 128, 1), blk, 0, stream>>>(
          x1, D_MODEL, wt + WT_1, wt + WT_1, wt + WT_1, D_MODEL,
          b1, b1, b1, ffmid, ffmid, ffmid, D_FF, D_MODEL, nullptr);

  // FF2 single launch (K=2048) + residual (x1): ffacc = ffmid@W2 + b2 + x1
  gemm_bf16_kernel<64, false, true>
      <<<dim3(D_MODEL / 64, NROWS / 64, 1), blk, 0, stream>>>(
          ffmid, D_FF, wt + WT_2, wt + WT_2, wt + WT_2, D_FF,
          b2, b2, b2, ffacc, ffacc, ffacc, D_MODEL, D_FF, x1);

  // LN2 -> fp32 output (overwrites wt scratch)
  ln_kernel<bf16, float><<<NROWS / 4, blk, 0, stream>>>(ffacc, g2, beta2, out);
}

// Round 14
// 207.271 us; speedup vs baseline: 1.1884x; 1.1627x over previous
//
#include <hip/hip_runtime.h>
#include <hip/hip_bf16.h>

// EncoderLayer: B=2, S=2048, D_MODEL=512, H=8, D_FF=2048
// Round 14: r12/r13 post-mortem -> dbuf halved occupancy (48KB=3blk/CU vs
// r10's 27.6KB=5blk/CU); on 8-32-iter K-loops TLP > intra-wave pipelining.
// Revert to r10 staging (single-buffer padded [72], prefetch, 2 barriers) and
// apply the proven tile lever (m93/m112: 64^2=343, 128^2=912 TF):
//  * QKV/FF1: BM=128 x BN=128 (4 waves, 64x64 quadrant each: RG=4, 32 MFMA
//    vs 16 frag-reads per barrier-pair; 36.9KB LDS -> 4 blk/CU).
//  * Wo/FF2:  BM=128 x BN=64 (grid (8,32)=256 blocks).
// Attention (r10, 44us), prep, LN unchanged.
// ws (MiB): q[0,4)->attn_out; k[4,8)->x1; v[8,12)->ffacc; ctx[12,16);
//   xb[16,20) (dead after Wo) -> ffmid[16,32).  Peak 32 MiB (proven).
// d_out first 6MB = transposed bf16 weights (LN2 overwrites at end).

#define D_MODEL 512
#define N_HEADS 8
#define D_K 64
#define D_FF 2048
#define BATCH 2
#define SEQ 2048
#define NROWS (BATCH * SEQ)

typedef __hip_bfloat16 bf16;
typedef __attribute__((ext_vector_type(8))) short bf16x8;
typedef __attribute__((ext_vector_type(4))) float f32x4;

__device__ __forceinline__ unsigned short f2b(float f) {
  union { bf16 b; unsigned short u; } cv;
  cv.b = __float2bfloat16(f);
  return cv.u;
}
__device__ __forceinline__ float b2f(unsigned short u) {
  return __uint_as_float(((unsigned int)u) << 16);
}
__device__ __forceinline__ float toF(const bf16 x) { return __bfloat162float(x); }
__device__ __forceinline__ float toF(const float x) { return x; }
__device__ __forceinline__ void storeC(float* p, float v) { *p = v; }
__device__ __forceinline__ void storeC(bf16* p, float v) {
  *p = __float2bfloat16(v);
}

__device__ __forceinline__ void ld8f(const float* p, float* v) {
  const float4 a = *(const float4*)p;
  const float4 b = *(const float4*)(p + 4);
  v[0] = a.x; v[1] = a.y; v[2] = a.z; v[3] = a.w;
  v[4] = b.x; v[5] = b.y; v[6] = b.z; v[7] = b.w;
}
__device__ __forceinline__ void ld8f(const bf16* p, float* v) {
  const bf16x8 u = *(const bf16x8*)p;
#pragma unroll
  for (int i = 0; i < 8; ++i) v[i] = b2f((unsigned short)u[i]);
}
__device__ __forceinline__ void st8f(float* p, const float* v) {
  *(float4*)p = make_float4(v[0], v[1], v[2], v[3]);
  *(float4*)(p + 4) = make_float4(v[4], v[5], v[6], v[7]);
}
__device__ __forceinline__ void st8f(bf16* p, const float* v) {
  bf16x8 u;
#pragma unroll
  for (int i = 0; i < 8; ++i) u[i] = (short)f2b(v[i]);
  *(bf16x8*)p = u;
}

// Wt element offsets inside the d_out scratch region
#define WT_Q 0
#define WT_K 262144
#define WT_V 524288
#define WT_O 786432
#define WT_1 1048576
#define WT_2 2097152

// ---------------------------------------------------------------------------
// prep: z<6: W[R][Cn] fp32 -> Wt[Cn][R] bf16 (transposed). z=6: x -> bf16.
// ---------------------------------------------------------------------------
__global__ __launch_bounds__(256) void prep_kernel(
    const float* __restrict__ Wq, const float* __restrict__ Wk,
    const float* __restrict__ Wv, const float* __restrict__ Wo,
    const float* __restrict__ W1, const float* __restrict__ W2,
    bf16* __restrict__ outw, const float* __restrict__ x,
    bf16* __restrict__ xb) {
  const int z = blockIdx.z;
  const int t = threadIdx.x;

  if (z == 6) {  // xconv
    const size_t base =
        ((size_t)(blockIdx.y * 32 + blockIdx.x) * 2048) + (size_t)t * 8;
    float v[8];
    ld8f(x + base, v);
    st8f(xb + base, v);
    return;
  }

  const float* W;
  int R, Cn;
  size_t off;
  if (z == 0)      { W = Wq; R = 512;  Cn = 512;  off = WT_Q; }
  else if (z == 1) { W = Wk; R = 512;  Cn = 512;  off = WT_K; }
  else if (z == 2) { W = Wv; R = 512;  Cn = 512;  off = WT_V; }
  else if (z == 3) { W = Wo; R = 512;  Cn = 512;  off = WT_O; }
  else if (z == 4) { W = W1; R = 512;  Cn = 2048; off = WT_1; }
  else             { W = W2; R = 2048; Cn = 512;  off = WT_2; }
  const int c0 = blockIdx.x * 64;
  const int r0 = blockIdx.y * 64;
  if (c0 >= Cn || r0 >= R) return;

  __shared__ short tile[64][72];  // [c][r]
  {
    const int r = t >> 2, cg = (t & 3) * 16;
    const float* src = &W[(size_t)(r0 + r) * Cn + c0 + cg];
#pragma unroll
    for (int i = 0; i < 4; ++i) {
      const float4 v = *(const float4*)(src + 4 * i);
      tile[cg + 4 * i + 0][r] = (short)f2b(v.x);
      tile[cg + 4 * i + 1][r] = (short)f2b(v.y);
      tile[cg + 4 * i + 2][r] = (short)f2b(v.z);
      tile[cg + 4 * i + 3][r] = (short)f2b(v.w);
    }
  }
  __syncthreads();
  {
    const int c = t >> 2, rg = (t & 3) * 16;
    short* dst = (short*)outw + off + (size_t)(c0 + c) * R + r0 + rg;
    *(bf16x8*)dst = *(const bf16x8*)&tile[c][rg];
    *(bf16x8*)(dst + 8) = *(const bf16x8*)&tile[c][rg + 8];
  }
}

// ---------------------------------------------------------------------------
// gemm_bf16<BM,BN,RELU,RESID>: C = A @ Wt^T + bias (+ R residual, ReLU).
// A[row][k] bf16 (lda), Wt[n][k] bf16 (ldk). BK=64, block=256 (4 waves).
// BN=128: waves in 2x2 quadrants (64x64 each, RG=4); BN=64: 4 row-bands
// (32x64, RG=2). r10 staging: single-buffer padded [72], register prefetch,
// 2 barriers/iter (5 blk/CU @BN=64, 4 @BN=128).
// Grid (Nview/BN, M/BM, NZ); z muxes (Wt,bias,C).
// ---------------------------------------------------------------------------
template <int BM, int BN, bool RELU, bool RESID>
__global__ __launch_bounds__(256) void gemm_bf16_kernel(
    const bf16* __restrict__ A, int lda,
    const bf16* __restrict__ Wt0, const bf16* __restrict__ Wt1,
    const bf16* __restrict__ Wt2, int ldk,
    const float* __restrict__ b0, const float* __restrict__ b1,
    const float* __restrict__ b2,
    bf16* __restrict__ C0, bf16* __restrict__ C1, bf16* __restrict__ C2,
    int ldc, int K, const bf16* __restrict__ R) {
  const bf16* Wt = (blockIdx.z == 0) ? Wt0 : (blockIdx.z == 1 ? Wt1 : Wt2);
  const float* bias = (blockIdx.z == 0) ? b0 : (blockIdx.z == 1 ? b1 : b2);
  bf16* C = (blockIdx.z == 0) ? C0 : (blockIdx.z == 1 ? C1 : C2);

  constexpr int WX = BN / 64;        // waves along N
  constexpr int WY = 4 / WX;         // waves along M
  constexpr int RG = BM / (16 * WY); // 16-row groups per wave
  constexpr int NA = BM / 32;        // A 16B-slots per thread
  constexpr int NW = BN / 32;        // W 16B-slots per thread

  __shared__ short as_[BM][72];
  __shared__ short bs[BN][72];

  const int rowBase = blockIdx.y * BM;
  const int colBase = blockIdx.x * BN;
  const int t = threadIdx.x;
  const int wave = t >> 6;
  const int lane = t & 63;
  const int quad = lane >> 4;
  const int l15 = lane & 15;
  const int wy = wave / WX;
  const int wx = wave % WX;

  const int arow = (NA == 2) ? (t >> 2) : (t >> 1);
  const int akc = (NA == 2) ? ((t & 3) * 16) : ((t & 1) * 32);
  const int wrow = (NW == 2) ? (t >> 2) : (t >> 1);
  const int wkc = (NW == 2) ? ((t & 3) * 16) : ((t & 1) * 32);

  const short* Abase = (const short*)A + (size_t)(rowBase + arow) * lda + akc;
  const short* Wbase = (const short*)Wt + (size_t)(colBase + wrow) * ldk + wkc;

  bf16x8 areg[NA], wreg[NW];
#pragma unroll
  for (int i = 0; i < NA; ++i) areg[i] = *(const bf16x8*)(Abase + 8 * i);
#pragma unroll
  for (int i = 0; i < NW; ++i) wreg[i] = *(const bf16x8*)(Wbase + 8 * i);

  f32x4 acc[RG][4];
#pragma unroll
  for (int i = 0; i < RG; ++i)
#pragma unroll
    for (int nt = 0; nt < 4; ++nt) acc[i][nt] = (f32x4){0.f, 0.f, 0.f, 0.f};

  for (int k0 = 0; k0 < K; k0 += 64) {
    // commit prefetched tile
#pragma unroll
    for (int i = 0; i < NA; ++i) *(bf16x8*)&as_[arow][akc + 8 * i] = areg[i];
#pragma unroll
    for (int i = 0; i < NW; ++i) *(bf16x8*)&bs[wrow][wkc + 8 * i] = wreg[i];

    // issue next tile's loads
    if (k0 + 64 < K) {
#pragma unroll
      for (int i = 0; i < NA; ++i)
        areg[i] = *(const bf16x8*)(Abase + k0 + 64 + 8 * i);
#pragma unroll
      for (int i = 0; i < NW; ++i)
        wreg[i] = *(const bf16x8*)(Wbase + k0 + 64 + 8 * i);
    }
    __syncthreads();

#pragma unroll
    for (int kc = 0; kc < 2; ++kc) {
      bf16x8 af[RG];
#pragma unroll
      for (int i = 0; i < RG; ++i)
        af[i] = *(const bf16x8*)
            &as_[wy * (16 * RG) + i * 16 + l15][quad * 8 + kc * 32];
#pragma unroll
      for (int nt = 0; nt < 4; ++nt) {
        const bf16x8 bfr = *(const bf16x8*)
            &bs[wx * 64 + nt * 16 + l15][quad * 8 + kc * 32];
#pragma unroll
        for (int i = 0; i < RG; ++i)
          acc[i][nt] = __builtin_amdgcn_mfma_f32_16x16x32_bf16(
              af[i], bfr, acc[i][nt], 0, 0, 0);
      }
    }
    __syncthreads();
  }

#pragma unroll
  for (int i = 0; i < RG; ++i)
#pragma unroll
    for (int nt = 0; nt < 4; ++nt) {
      const int col = colBase + wx * 64 + nt * 16 + l15;
#pragma unroll
      for (int r = 0; r < 4; ++r) {
        const int row = rowBase + wy * (16 * RG) + i * 16 + quad * 4 + r;
        float v = acc[i][nt][r] + bias[col];
        if (RESID) v += toF(R[(size_t)row * ldc + col]);
        if (RELU) v = fmaxf(v, 0.f);
        storeC(&C[(size_t)row * ldc + col], v);
      }
    }
}

// ---------------------------------------------------------------------------
// MFMA flash attention, RG=2 (r10, unchanged). grid (SEQ/128, B*H), block 512.
// ---------------------------------------------------------------------------
__global__ __launch_bounds__(512) void attn_mfma_kernel(
    const bf16* __restrict__ Q, const bf16* __restrict__ Km,
    const bf16* __restrict__ V, const int* __restrict__ mask,
    bf16* __restrict__ ctx) {
  const int qt = blockIdx.x;
  const int bh = blockIdx.y;
  const int b = bh >> 3;
  const int h = bh & 7;
  const int t = threadIdx.x;
  const int wave = t >> 6;
  const int half = wave >> 2;
  const int wq = wave & 3;
  const int lane = t & 63;
  const int quad = lane >> 4;
  const int l15 = lane & 15;

  __shared__ __align__(16) char smem[74240];
  auto ks = (short(*)[64][72])(smem);
  auto vt = (short(*)[64][72])(smem + 18432);
  auto pb = (short(*)[32][72])(smem + 36864);
  auto mk = (int(*)[64])(smem + 73728);
  auto mg = (float(*)[32][68])(smem);  // aliases ks/vt/pb after final barrier

  bf16x8 qf[2][2];
#pragma unroll
  for (int rg = 0; rg < 2; ++rg) {
    const short* qg = (const short*)Q +
        (size_t)(b * SEQ + qt * 128 + wq * 32 + rg * 16 + l15) * D_MODEL +
        h * D_K + quad * 8;
    qf[rg][0] = *(const bf16x8*)qg;
    qf[rg][1] = *(const bf16x8*)(qg + 32);
  }

  f32x4 of[2][4];
#pragma unroll
  for (int rg = 0; rg < 2; ++rg)
#pragma unroll
    for (int nt = 0; nt < 4; ++nt) of[rg][nt] = (f32x4){0.f, 0.f, 0.f, 0.f};
  float l_acc[2][4] = {{0.f, 0.f, 0.f, 0.f}, {0.f, 0.f, 0.f, 0.f}};

  const int hs = t >> 8;
  const int tt = t & 255;
  const int kr = tt >> 2, kc0 = (tt & 3) * 16;
  const int vk = tt & 63, vc0 = ((tt >> 6) & 3) * 16;

  bf16x8 kv0, kv1, vv0, vv1;
  int mv = 1;
  {
    const int keyRow = (hs * 16 + 0) * 64;
    const short* kg = (const short*)Km +
        (size_t)(b * SEQ + keyRow + kr) * D_MODEL + h * D_K + kc0;
    kv0 = *(const bf16x8*)kg;
    kv1 = *(const bf16x8*)(kg + 8);
    const short* vg = (const short*)V +
        (size_t)(b * SEQ + keyRow + vk) * D_MODEL + h * D_K + vc0;
    vv0 = *(const bf16x8*)vg;
    vv1 = *(const bf16x8*)(vg + 8);
    if (tt < 64) mv = mask[b * SEQ + keyRow + tt];
  }

  for (int kt = 0; kt < 16; ++kt) {
    *(bf16x8*)&ks[hs][kr][kc0] = kv0;
    *(bf16x8*)&ks[hs][kr][kc0 + 8] = kv1;
#pragma unroll
    for (int i = 0; i < 8; ++i) vt[hs][vc0 + i][vk] = vv0[i];
#pragma unroll
    for (int i = 0; i < 8; ++i) vt[hs][vc0 + 8 + i][vk] = vv1[i];
    if (tt < 64) mk[hs][tt] = mv;

    if (kt + 1 < 16) {
      const int keyRow = (hs * 16 + kt + 1) * 64;
      const short* kg = (const short*)Km +
          (size_t)(b * SEQ + keyRow + kr) * D_MODEL + h * D_K + kc0;
      kv0 = *(const bf16x8*)kg;
      kv1 = *(const bf16x8*)(kg + 8);
      const short* vg = (const short*)V +
          (size_t)(b * SEQ + keyRow + vk) * D_MODEL + h * D_K + vc0;
      vv0 = *(const bf16x8*)vg;
      vv1 = *(const bf16x8*)(vg + 8);
      if (tt < 64) mv = mask[b * SEQ + keyRow + tt];
    }
    __syncthreads();

    f32x4 sf[2][4];
#pragma unroll
    for (int nt = 0; nt < 4; ++nt) {
      const bf16x8 kf0 = *(const bf16x8*)&ks[half][l15 + 16 * nt][quad * 8];
      const bf16x8 kf1 =
          *(const bf16x8*)&ks[half][l15 + 16 * nt][quad * 8 + 32];
#pragma unroll
      for (int rg = 0; rg < 2; ++rg) {
        f32x4 acc = (f32x4){0.f, 0.f, 0.f, 0.f};
        acc = __builtin_amdgcn_mfma_f32_16x16x32_bf16(qf[rg][0], kf0, acc, 0, 0, 0);
        acc = __builtin_amdgcn_mfma_f32_16x16x32_bf16(qf[rg][1], kf1, acc, 0, 0, 0);
        sf[rg][nt] = acc;
      }
    }

#pragma unroll
    for (int nt = 0; nt < 4; ++nt) {
      const bool dead = (mk[half][l15 + 16 * nt] == 0);
#pragma unroll
      for (int rg = 0; rg < 2; ++rg)
#pragma unroll
        for (int r = 0; r < 4; ++r) {
          float p = __expf(fmaf(sf[rg][nt][r], 0.125f, -8.f));
          if (dead) p = 0.f;
          l_acc[rg][r] += p;
          pb[wave][rg * 16 + quad * 4 + r][l15 + 16 * nt] = (short)f2b(p);
        }
    }

#pragma unroll
    for (int kc = 0; kc < 2; ++kc) {
      bf16x8 pf[2];
#pragma unroll
      for (int rg = 0; rg < 2; ++rg)
        pf[rg] = *(const bf16x8*)&pb[wave][rg * 16 + l15][kc * 32 + quad * 8];
#pragma unroll
      for (int nt = 0; nt < 4; ++nt) {
        const bf16x8 vf =
            *(const bf16x8*)&vt[half][l15 + 16 * nt][kc * 32 + quad * 8];
#pragma unroll
        for (int rg = 0; rg < 2; ++rg)
          of[rg][nt] = __builtin_amdgcn_mfma_f32_16x16x32_bf16(
              pf[rg], vf, of[rg][nt], 0, 0, 0);
      }
    }
    __syncthreads();
  }

#pragma unroll
  for (int xm = 1; xm < 16; xm <<= 1)
#pragma unroll
    for (int rg = 0; rg < 2; ++rg)
#pragma unroll
      for (int r = 0; r < 4; ++r)
        l_acc[rg][r] += __shfl_xor(l_acc[rg][r], xm, 64);

#pragma unroll
  for (int rg = 0; rg < 2; ++rg)
#pragma unroll
    for (int nt = 0; nt < 4; ++nt)
#pragma unroll
      for (int r = 0; r < 4; ++r)
        mg[wave][rg * 16 + quad * 4 + r][l15 + 16 * nt] = of[rg][nt][r];
  if (l15 == 0) {
#pragma unroll
    for (int rg = 0; rg < 2; ++rg)
#pragma unroll
      for (int r = 0; r < 4; ++r)
        mg[wave][rg * 16 + quad * 4 + r][64] = l_acc[rg][r];
  }
  __syncthreads();

  if (wave < 4) {
    const int pw = wave + 4;
#pragma unroll
    for (int rg = 0; rg < 2; ++rg)
#pragma unroll
      for (int r = 0; r < 4; ++r) {
        const int qrow = rg * 16 + quad * 4 + r;
        const float inv = 1.f / (l_acc[rg][r] + mg[pw][qrow][64]);
        const int row = qt * 128 + wave * 32 + qrow;
        bf16* cp = ctx + (size_t)(b * SEQ + row) * D_MODEL + h * D_K;
#pragma unroll
        for (int nt = 0; nt < 4; ++nt)
          cp[l15 + 16 * nt] = __float2bfloat16(
              (of[rg][nt][r] + mg[pw][qrow][l15 + 16 * nt]) * inv);
      }
  }
}

// ---------------------------------------------------------------------------
// Wave-per-row LayerNorm (single input): out = LN(base)*g+beta.
// block 256 = 4 rows, grid NROWS/4. Shfl butterfly only.
// ---------------------------------------------------------------------------
template <typename BT, typename OT>
__global__ __launch_bounds__(256) void ln_kernel(
    const BT* __restrict__ base, const float* __restrict__ g,
    const float* __restrict__ beta, OT* __restrict__ out) {
  const int wave = threadIdx.x >> 6;
  const int lane = threadIdx.x & 63;
  const int row = blockIdx.x * 4 + wave;
  const size_t rb = (size_t)row * D_MODEL + lane * 8;

  float v[8];
  ld8f(base + rb, v);

  float s = 0.f;
#pragma unroll
  for (int i = 0; i < 8; ++i) s += v[i];
#pragma unroll
  for (int xm = 1; xm < 64; xm <<= 1) s += __shfl_xor(s, xm, 64);
  const float mu = s * (1.f / (float)D_MODEL);

  float q = 0.f;
#pragma unroll
  for (int i = 0; i < 8; ++i) {
    v[i] -= mu;
    q += v[i] * v[i];
  }
#pragma unroll
  for (int xm = 1; xm < 64; xm <<= 1) q += __shfl_xor(q, xm, 64);
  const float rs = rsqrtf(q * (1.f / (float)D_MODEL) + 1e-5f);

  float gv[8], bv[8];
  ld8f(g + lane * 8, gv);
  ld8f(beta + lane * 8, bv);
#pragma unroll
  for (int i = 0; i < 8; ++i) v[i] = v[i] * rs * gv[i] + bv[i];
  st8f(out + rb, v);
}

// ---------------------------------------------------------------------------
extern "C" void kernel_launch(void* const* d_in, const int* in_sizes, int n_in,
                              void* d_out, int out_size, void* d_ws, size_t ws_size,
                              hipStream_t stream) {
  const float* x     = (const float*)d_in[0];
  const int*   mask  = (const int*)d_in[1];
  const float* Wq    = (const float*)d_in[2];
  const float* bq    = (const float*)d_in[3];
  const float* Wk    = (const float*)d_in[4];
  const float* bk    = (const float*)d_in[5];
  const float* Wv    = (const float*)d_in[6];
  const float* bv    = (const float*)d_in[7];
  const float* Wo    = (const float*)d_in[8];
  const float* bo    = (const float*)d_in[9];
  const float* W1    = (const float*)d_in[10];
  const float* b1    = (const float*)d_in[11];
  const float* W2    = (const float*)d_in[12];
  const float* b2    = (const float*)d_in[13];
  const float* g1    = (const float*)d_in[14];
  const float* beta1 = (const float*)d_in[15];
  const float* g2    = (const float*)d_in[16];
  const float* beta2 = (const float*)d_in[17];
  float* out = (float*)d_out;

  char* ws = (char*)d_ws;
  const size_t MB4 = (size_t)NROWS * D_MODEL * sizeof(bf16);  // 4 MiB
  bf16* q        = (bf16*)(ws + 0 * MB4);
  bf16* kbuf     = (bf16*)(ws + 1 * MB4);
  bf16* vbuf     = (bf16*)(ws + 2 * MB4);
  bf16* ctx      = (bf16*)(ws + 3 * MB4);
  bf16* xb       = (bf16*)(ws + 4 * MB4);  // [16,20), dead after Wo
  bf16* attn_out = q;                      // q dead after attention
  bf16* x1       = kbuf;                   // k dead after attention
  bf16* ffacc    = vbuf;                   // v dead after attention
  bf16* ffmid    = (bf16*)(ws + 4 * MB4);  // [16,32), xb dead after Wo

  bf16* wt = (bf16*)d_out;  // 6MB transposed bf16 weights (LN2 overwrites)

  const dim3 blk(256);

  // prep: weights -> bf16 transposed; x -> bf16 (z=6)
  prep_kernel<<<dim3(32, 32, 7), blk, 0, stream>>>(Wq, Wk, Wv, Wo, W1, W2, wt,
                                                   x, xb);

  // QKV fused, 128x128 tile
  gemm_bf16_kernel<128, 128, false, false>
      <<<dim3(D_MODEL / 128, NROWS / 128, 3), blk, 0, stream>>>(
          xb, D_MODEL, wt + WT_Q, wt + WT_K, wt + WT_V, D_MODEL,
          bq, bk, bv, q, kbuf, vbuf, D_MODEL, D_MODEL, nullptr);

  // attention (RG=2: 128 q rows per block)
  attn_mfma_kernel<<<dim3(SEQ / 128, BATCH * N_HEADS), dim3(512), 0, stream>>>(
      q, kbuf, vbuf, mask, ctx);

  // Wo projection + residual (xb), 128x64 tile: attn_out = ctx@Wo + bo + x
  gemm_bf16_kernel<128, 64, false, true>
      <<<dim3(D_MODEL / 64, NROWS / 128, 1), blk, 0, stream>>>(
          ctx, D_MODEL, wt + WT_O, wt + WT_O, wt + WT_O, D_MODEL,
          bo, bo, bo, attn_out, attn_out, attn_out, D_MODEL, D_MODEL, xb);

  // LN1: x1 = LN(attn_out) -> bf16
  ln_kernel<bf16, bf16><<<NROWS / 4, blk, 0, stream>>>(attn_out, g1, beta1, x1);

  // FF1, 128x128 tile: ffmid = relu(x1 @ W1 + b1), N=2048
  gemm_bf16_kernel<128, 128, true, false>
      <<<dim3(D_FF / 128, NROWS / 128, 1), blk, 0, stream>>>(
          x1, D_MODEL, wt + WT_1, wt + WT_1, wt + WT_1, D_MODEL,
          b1, b1, b1, ffmid, ffmid, ffmid, D_FF, D_MODEL, nullptr);

  // FF2 (K=2048) + residual (x1), 128x64 tile: ffacc = ffmid@W2 + b2 + x1
  gemm_bf16_kernel<128, 64, false, true>
      <<<dim3(D_MODEL / 64, NROWS / 128, 1), blk, 0, stream>>>(
          ffmid, D_FF, wt + WT_2, wt + WT_2, wt + WT_2, D_FF,
          b2, b2, b2, ffacc, ffacc, ffacc, D_MODEL, D_FF, x1);

  // LN2 -> fp32 output (overwrites wt scratch)
  ln_kernel<bf16, float><<<NROWS / 4, blk, 0, stream>>>(ffacc, g2, beta2, out);
}